// Round 11
// baseline (429.472 us; speedup 1.0000x reference)
//
#include <hip/hip_runtime.h>
#include <hip/hip_bf16.h>
#include <hip/hip_fp16.h>

// SFM model: B=256, T=128, D=128, FREQ=16, HID=128
// Phase 1: P[(b*128+t)*528 + c] = x(b,t,:) @ [W_i|W_ste|W_c|W_o|W_fre] + bias
// Phase 2: sequential scan, 1024 thr/block, 1 batch/block.
//   U matrices live in LDS as packed fp16 pairs (128 KB) -- compiler-proof
//   (rounds 4/7/9: VGPR path refused, U streamed from L2 = entire 261 us).
//   h stays fp32 (readlane broadcast); fma(f16->f32) = v_fma_mix_f32.

__device__ __forceinline__ float hsig_f(float z) {
    return fminf(fmaxf(z * (1.0f / 6.0f) + 0.5f, 0.0f), 1.0f);
}

// ---------------- Phase 1: projection GEMM ----------------
__global__ __launch_bounds__(256) void proj_gemm(
    const float* __restrict__ input,
    const float* __restrict__ Wi, const float* __restrict__ Wste,
    const float* __restrict__ Wc, const float* __restrict__ Wo,
    const float* __restrict__ Wfre,
    const float* __restrict__ bi, const float* __restrict__ bste,
    const float* __restrict__ bc, const float* __restrict__ bo,
    const float* __restrict__ bfre,
    float* __restrict__ P)
{
    __shared__ __align__(16) float XT[128 * 64];  // [k][t]  32 KB
    __shared__ __align__(16) float WT[128 * 66];  // [k][c]  stride 66 dwords

    const int br  = blockIdx.x;          // 512 blocks: 64 rows each
    const int b   = br >> 1;
    const int t0g = (br & 1) * 64;
    const int tid = threadIdx.x;

    const float* xb = input + (size_t)b * 16384 + t0g;
#pragma unroll
    for (int i = 0; i < 8; i++) {
        int f = (i * 256 + tid) * 4;
        int k = f >> 6, t = f & 63;
        *(float4*)(&XT[k * 64 + t]) = *(const float4*)(xb + k * 128 + t);
    }

    const int tx = tid & 31;   // col pair
    const int ty = tid >> 5;   // row group: rows ty*8 .. ty*8+7

    const float* Ws[5]     = {Wi, Wste, Wc, Wo, Wfre};
    const float* biases[5] = {bi, bste, bc, bo, bfre};

    for (int ct = 0; ct < 5; ct++) {
        const float* W     = Ws[ct];
        const float* bias  = biases[ct];
        const int    ncols = (ct < 4) ? 128 : 16;
        const int    npass = (ct < 4) ? 2 : 1;
        const int    cbase = (ct < 4) ? ct * 128 : 512;

        for (int ch = 0; ch < npass; ch++) {
            __syncthreads();
#pragma unroll
            for (int i = 0; i < 8; i++) {
                int f = (i * 256 + tid) * 4;
                int k = f >> 6, c = f & 63;
                int gc = ch * 64 + c;
                if (gc < ncols)
                    *(float4*)(&WT[k * 66 + c]) = *(const float4*)(W + k * ncols + gc);
            }
            __syncthreads();

            float acc[8][2] = {};
#pragma unroll 4
            for (int k = 0; k < 128; k++) {
                float2 w  = *(const float2*)(&WT[k * 66 + tx * 2]);
                float4 x0 = *(const float4*)(&XT[k * 64 + ty * 8]);
                float4 x1 = *(const float4*)(&XT[k * 64 + ty * 8 + 4]);
                const float xr[8] = {x0.x, x0.y, x0.z, x0.w, x1.x, x1.y, x1.z, x1.w};
#pragma unroll
                for (int r = 0; r < 8; r++) {
                    acc[r][0] = fmaf(xr[r], w.x, acc[r][0]);
                    acc[r][1] = fmaf(xr[r], w.y, acc[r][1]);
                }
            }

            const int colg = ch * 64 + tx * 2;
            if (colg < ncols) {
                float b0 = bias[colg], b1 = bias[colg + 1];
#pragma unroll
                for (int r = 0; r < 8; r++) {
                    int row = br * 64 + ty * 8 + r;
                    float2 o = make_float2(acc[r][0] + b0, acc[r][1] + b1);
                    *(float2*)(&P[(size_t)row * 528 + cbase + colg]) = o;
                }
            }
        }
    }
}

// ---------------- Phase 2: sequential recurrence ----------------
// 1024 threads. tid -> half = tid>>9 (k-split), c = tid&511, m = c>>7, j = c&127.
// U in LDS: u16_lds[m][kk][j] = half2{ U_m[2kk][j], U_m[2kk+1][j] }  (128 KB)
// State ownership: hh = tid>>3 (0..127), fsel = tid&7 -> freqs {fsel, fsel+8}.
__global__ __launch_bounds__(1024) void recur_kernel(
    const float* __restrict__ P,
    const float* __restrict__ Ui, const float* __restrict__ Uste,
    const float* __restrict__ Uc, const float* __restrict__ Uo,
    const float* __restrict__ Ufre,
    const float* __restrict__ Ua, const float* __restrict__ ba_g,
    const float* __restrict__ Wsym, const float* __restrict__ bsym,
    float* __restrict__ out)
{
    __shared__ __half2 u16_lds[4 * 64 * 128];  // 128 KB  [m][kpair][j]
    __shared__ float ufre_t[16 * 132];         // [col][k] 8.25 KB
    __shared__ float costab[16], sintab[16];
    __shared__ float gate_buf[512];            // [i|ste|c|o] x 128
    __shared__ float partial_buf[512];         // half-1 matvec partials
    __shared__ float fre_buf[16];
    __shared__ float h_buf[128];

    const int tid  = threadIdx.x;
    const int lane = tid & 63;
    const int half = tid >> 9;
    const int c    = tid & 511;
    const int m    = c >> 7;
    const int j    = c & 127;
    const int hh   = tid >> 3;     // 0..127
    const int fsel = tid & 7;      // freqs fsel, fsel+8
    const int b    = blockIdx.x;

    // ---- one-time LDS init ----
    // U -> packed fp16 pairs. e -> m_=e>>13, kk=(e>>7)&63, jj=e&127 (coalesced over jj).
    for (int e = tid; e < 4 * 64 * 128; e += 1024) {
        int m_ = e >> 13, rem = e & 8191, kk = rem >> 7, jj = rem & 127;
        const float* Um = (m_ == 0) ? Ui : (m_ == 1) ? Uste : (m_ == 2) ? Uc : Uo;
        float lo = Um[(2 * kk) * 128 + jj];
        float hi = Um[(2 * kk + 1) * 128 + jj];
        u16_lds[e] = __floats2half2_rn(lo, hi);
    }
    for (int e = tid; e < 2048; e += 1024) {
        int k = e >> 4, col = e & 15;
        ufre_t[col * 132 + k] = Ufre[e];
    }
    if (tid < 16) {
        float ang = 6.283185307179586f * (float)tid * (1.0f / 16.0f);
        costab[tid] = cosf(ang);
        sintab[tid] = sinf(ang);
    }
    if (tid < 128) h_buf[tid] = 0.0f;

    const float ua0 = Ua[fsel];
    const float ua1 = Ua[fsel + 8];
    const float ba  = ba_g[hh];

    float hA = 0.0f;               // h[half*64 + lane], wave-replicated
    float Sre0 = 0.f, Sim0 = 0.f, Sre1 = 0.f, Sim1 = 0.f;
    int idx0 = 0, idx1 = 0;

    __syncthreads();

    // per-thread U column base: [m][half*32 + kk][j], stride 128 half2 per kk
    const __half2* ucol = &u16_lds[(m << 13) + (half << 12) + j];

    const float* pr = P + (size_t)b * 128 * 528;
    for (int t = 0; t < 128; t++) {
        const float xpre = (half == 0) ? pr[c] : pr[512 + (c >> 5)];

        // ---- matvec partial: acc = sum_{k in half} h[k] * U[k][j] ----
        // ds_read_b32 (conflict-free: lanes -> consecutive dwords) + fma_mix
        float a0 = 0.f, a1 = 0.f;
#pragma unroll
        for (int kk = 0; kk < 32; kk++) {
            __half2 uh = ucol[kk << 7];
            float s0 = __uint_as_float(__builtin_amdgcn_readlane(__float_as_uint(hA), 2 * kk));
            float s1 = __uint_as_float(__builtin_amdgcn_readlane(__float_as_uint(hA), 2 * kk + 1));
            a0 = fmaf(__low2float(uh),  s0, a0);
            a1 = fmaf(__high2float(uh), s1, a1);
        }
        float acc = a0 + a1;

        if (half) partial_buf[c] = acc;
        __syncthreads();  // B1: partials visible

        if (half == 0) {
            float z = acc + partial_buf[c] + xpre;
            float g = (m == 2) ? tanhf(z) : hsig_f(z);
            gate_buf[c] = g;
        } else {
            // fre gate: col = c>>5, 32 threads per col, 4 k's each (h_buf = old h)
            const int col = c >> 5, kg = c & 31;
            float4 hv = *(const float4*)(&h_buf[kg * 4]);
            float4 uv = *(const float4*)(&ufre_t[col * 132 + kg * 4]);
            float p = fmaf(hv.x, uv.x, fmaf(hv.y, uv.y, fmaf(hv.z, uv.z, hv.w * uv.w)));
#pragma unroll
            for (int off = 1; off <= 16; off <<= 1) p += __shfl_xor(p, off, 64);
            if (kg == 0) fre_buf[col] = hsig_f(p + xpre);
        }
        __syncthreads();  // B2: gates + fre ready

        // ---- state update: thread owns (hh, freqs fsel & fsel+8) ----
        {
            float iv = gate_buf[hh];
            float sv = gate_buf[128 + hh];
            float tc = gate_buf[256 + hh];
            float ov = gate_buf[384 + hh];
            float cg = iv * tc;

            idx0 = (idx0 + fsel) & 15;
            idx1 = (idx1 + fsel + 8) & 15;

            float f0v = sv * fre_buf[fsel];
            float f1v = sv * fre_buf[fsel + 8];
            Sre0 = fmaf(f0v, Sre0, cg * costab[idx0]);
            Sim0 = fmaf(f0v, Sim0, cg * sintab[idx0]);
            Sre1 = fmaf(f1v, Sre1, cg * costab[idx1]);
            Sim1 = fmaf(f1v, Sim1, cg * sintab[idx1]);

            float aacc = fmaf(Sre0, Sre0, Sim0 * Sim0) * ua0;
            aacc = fmaf(fmaf(Sre1, Sre1, Sim1 * Sim1), ua1, aacc);
            aacc += __shfl_xor(aacc, 1, 64);
            aacc += __shfl_xor(aacc, 2, 64);
            aacc += __shfl_xor(aacc, 4, 64);
            if (fsel == 0) {
                float a = tanhf(aacc + ba);
                h_buf[hh] = ov * a;
            }
        }
        __syncthreads();  // B3: h ready
        hA = h_buf[half * 64 + lane];
        pr += 528;
    }

    // ---- output: out[b] = h @ W_sym + b_sym ----
    if (tid < 64) {
        float v = fmaf(h_buf[lane], Wsym[lane], h_buf[64 + lane] * Wsym[64 + lane]);
#pragma unroll
        for (int off = 1; off <= 32; off <<= 1) v += __shfl_xor(v, off, 64);
        if (lane == 0) out[b] = v + bsym[0];
    }
}

extern "C" void kernel_launch(void* const* d_in, const int* in_sizes, int n_in,
                              void* d_out, int out_size, void* d_ws, size_t ws_size,
                              hipStream_t stream) {
    const float* input = (const float*)d_in[0];
    const float* W_i   = (const float*)d_in[1];
    const float* U_i   = (const float*)d_in[2];
    const float* b_i   = (const float*)d_in[3];
    const float* W_ste = (const float*)d_in[4];
    const float* U_ste = (const float*)d_in[5];
    const float* b_ste = (const float*)d_in[6];
    const float* W_fre = (const float*)d_in[7];
    const float* U_fre = (const float*)d_in[8];
    const float* b_fre = (const float*)d_in[9];
    const float* W_c   = (const float*)d_in[10];
    const float* U_c   = (const float*)d_in[11];
    const float* b_c   = (const float*)d_in[12];
    const float* W_o   = (const float*)d_in[13];
    const float* U_o   = (const float*)d_in[14];
    const float* b_o   = (const float*)d_in[15];
    const float* U_a   = (const float*)d_in[16];
    const float* b_a   = (const float*)d_in[17];
    const float* W_sym = (const float*)d_in[18];
    const float* b_sym = (const float*)d_in[19];

    float* P = (float*)d_ws;  // 32768 x 528 fp32 = 69.2 MB

    proj_gemm<<<512, 256, 0, stream>>>(
        input, W_i, W_ste, W_c, W_o, W_fre,
        b_i, b_ste, b_c, b_o, b_fre, P);

    recur_kernel<<<256, 1024, 0, stream>>>(
        P, U_i, U_ste, U_c, U_o, U_fre,
        U_a, b_a, W_sym, b_sym, (float*)d_out);
}

// Round 13
// 363.849 us; speedup vs baseline: 1.1804x; 1.1804x over previous
//
#include <hip/hip_runtime.h>
#include <hip/hip_bf16.h>
#include <hip/hip_fp16.h>

// SFM model: B=256, T=128, D=128, FREQ=16, HID=128
// Phase 1: P[(b*128+t)*528 + c] = x(b,t,:) @ [W_i|W_ste|W_c|W_o|W_fre] + bias
// Phase 2: sequential scan, 1024 thr/block, 1 batch/block, 2 barriers/step.
//   U in LDS as packed fp16 (128 KB). h additionally mirrored as fp16 in LDS.
//   Matvec: threads 0-511 own one full column via v_dot2_f32_f16
//   (1 b128 h-broadcast + 4 b32 U + 4 dot2 per 8 MACs); threads 512-1023
//   compute the fre gate concurrently. Round-11 post-mortem: removing L2
//   traffic didn't help -> kernel is VALU-issue+barrier bound, so this round
//   halves instructions (no readlane) and removes one barrier (no split-K).

typedef _Float16 h2t __attribute__((ext_vector_type(2)));

__device__ __forceinline__ h2t bch(unsigned int v) {
    union { unsigned int u; h2t h; } c; c.u = v; return c.h;
}
__device__ __forceinline__ float dot2f(unsigned int u, unsigned int h, float acc) {
#if __has_builtin(__builtin_amdgcn_fdot2)
    return __builtin_amdgcn_fdot2(bch(u), bch(h), acc, false);
#else
    h2t a = bch(u), b = bch(h);
    acc = fmaf((float)a[0], (float)b[0], acc);
    return fmaf((float)a[1], (float)b[1], acc);
#endif
}

__device__ __forceinline__ float hsig_f(float z) {
    return fminf(fmaxf(z * (1.0f / 6.0f) + 0.5f, 0.0f), 1.0f);
}

// ---------------- Phase 1: projection GEMM ----------------
__global__ __launch_bounds__(256) void proj_gemm(
    const float* __restrict__ input,
    const float* __restrict__ Wi, const float* __restrict__ Wste,
    const float* __restrict__ Wc, const float* __restrict__ Wo,
    const float* __restrict__ Wfre,
    const float* __restrict__ bi, const float* __restrict__ bste,
    const float* __restrict__ bc, const float* __restrict__ bo,
    const float* __restrict__ bfre,
    float* __restrict__ P)
{
    __shared__ __align__(16) float XT[128 * 64];  // [k][t]  32 KB
    __shared__ __align__(16) float WT[128 * 66];  // [k][c]

    const int br  = blockIdx.x;          // 512 blocks: 64 rows each
    const int b   = br >> 1;
    const int t0g = (br & 1) * 64;
    const int tid = threadIdx.x;

    const float* xb = input + (size_t)b * 16384 + t0g;
#pragma unroll
    for (int i = 0; i < 8; i++) {
        int f = (i * 256 + tid) * 4;
        int k = f >> 6, t = f & 63;
        *(float4*)(&XT[k * 64 + t]) = *(const float4*)(xb + k * 128 + t);
    }

    const int tx = tid & 31;   // col pair
    const int ty = tid >> 5;   // rows ty*8 .. ty*8+7

    const float* Ws[5]     = {Wi, Wste, Wc, Wo, Wfre};
    const float* biases[5] = {bi, bste, bc, bo, bfre};

    for (int ct = 0; ct < 5; ct++) {
        const float* W     = Ws[ct];
        const float* bias  = biases[ct];
        const int    ncols = (ct < 4) ? 128 : 16;
        const int    npass = (ct < 4) ? 2 : 1;
        const int    cbase = (ct < 4) ? ct * 128 : 512;

        for (int ch = 0; ch < npass; ch++) {
            __syncthreads();
#pragma unroll
            for (int i = 0; i < 8; i++) {
                int f = (i * 256 + tid) * 4;
                int k = f >> 6, c = f & 63;
                int gc = ch * 64 + c;
                if (gc < ncols)
                    *(float4*)(&WT[k * 66 + c]) = *(const float4*)(W + k * ncols + gc);
            }
            __syncthreads();

            float acc[8][2] = {};
#pragma unroll 4
            for (int k = 0; k < 128; k++) {
                float2 w  = *(const float2*)(&WT[k * 66 + tx * 2]);
                float4 x0 = *(const float4*)(&XT[k * 64 + ty * 8]);
                float4 x1 = *(const float4*)(&XT[k * 64 + ty * 8 + 4]);
                const float xr[8] = {x0.x, x0.y, x0.z, x0.w, x1.x, x1.y, x1.z, x1.w};
#pragma unroll
                for (int r = 0; r < 8; r++) {
                    acc[r][0] = fmaf(xr[r], w.x, acc[r][0]);
                    acc[r][1] = fmaf(xr[r], w.y, acc[r][1]);
                }
            }

            const int colg = ch * 64 + tx * 2;
            if (colg < ncols) {
                float b0 = bias[colg], b1 = bias[colg + 1];
#pragma unroll
                for (int r = 0; r < 8; r++) {
                    int row = br * 64 + ty * 8 + r;
                    float2 o = make_float2(acc[r][0] + b0, acc[r][1] + b1);
                    *(float2*)(&P[(size_t)row * 528 + cbase + colg]) = o;
                }
            }
        }
    }
}

// ---------------- Phase 2: sequential recurrence ----------------
// 1024 threads. tid<512: full-column matvec+gate (c=tid, m=c>>7, j=c&127).
// tid>=512: fre gate (col=(tid-512)>>5, kg=(tid-512)&31).
// State: hh = tid>>3 (0..127), fsel = tid&7 -> freqs {fsel, fsel+8}.
// U LDS layout: u_lds[(m<<13) + (kk<<7) + j] = half2{U_m[2kk][j], U_m[2kk+1][j]}
__global__ __launch_bounds__(1024) void recur_kernel(
    const float* __restrict__ P,
    const float* __restrict__ Ui, const float* __restrict__ Uste,
    const float* __restrict__ Uc, const float* __restrict__ Uo,
    const float* __restrict__ Ufre,
    const float* __restrict__ Ua, const float* __restrict__ ba_g,
    const float* __restrict__ Wsym, const float* __restrict__ bsym,
    float* __restrict__ out)
{
    __shared__ __align__(16) unsigned int u_lds[4 * 64 * 128];  // 128 KB
    __shared__ __align__(16) float ufre_t[16 * 132];            // [col][k]
    __shared__ __align__(16) __half h16[128];                   // h as fp16
    __shared__ float costab[16], sintab[16];
    __shared__ float gate_buf[512];                             // [i|ste|c|o] x 128
    __shared__ float fre_buf[16];
    __shared__ float h_buf[128];

    const int tid  = threadIdx.x;
    const int b    = blockIdx.x;
    const int hh   = tid >> 3;     // 0..127
    const int fsel = tid & 7;      // freqs fsel, fsel+8

    const bool is_col = (tid < 512);
    const int  c   = tid & 511;    // col id (col threads)
    const int  m   = c >> 7;
    const int  j   = c & 127;
    const int  fcol = c >> 5;      // fre col (fre threads): 0..15
    const int  kg   = c & 31;      // fre k-group

    // ---- one-time LDS init ----
    for (int e = tid; e < 4 * 64 * 128; e += 1024) {
        int m_ = e >> 13, rem = e & 8191, kk = rem >> 7, jj = rem & 127;
        const float* Um = (m_ == 0) ? Ui : (m_ == 1) ? Uste : (m_ == 2) ? Uc : Uo;
        union { h2t h; unsigned int u; } p;
        p.h[0] = (_Float16)Um[(2 * kk) * 128 + jj];
        p.h[1] = (_Float16)Um[(2 * kk + 1) * 128 + jj];
        u_lds[e] = p.u;
    }
    for (int e = tid; e < 2048; e += 1024) {
        int k = e >> 4, col = e & 15;
        ufre_t[col * 132 + k] = Ufre[e];
    }
    if (tid < 16) {
        float ang = 6.283185307179586f * (float)tid * (1.0f / 16.0f);
        costab[tid] = cosf(ang);
        sintab[tid] = sinf(ang);
    }
    if (tid < 128) { h_buf[tid] = 0.0f; h16[tid] = __float2half(0.0f); }

    const float ua0 = Ua[fsel];
    const float ua1 = Ua[fsel + 8];
    const float ba  = ba_g[hh];

    float Sre0 = 0.f, Sim0 = 0.f, Sre1 = 0.f, Sim1 = 0.f;
    int idx0 = 0, idx1 = 0;

    __syncthreads();

    const unsigned int* ucol = u_lds + (m << 13) + j;   // stride 128 dwords per kk
    const uint4* h4 = (const uint4*)h16;                // 16 x (8 halves)

    const float* pr = P + (size_t)b * 128 * 528;
    for (int t = 0; t < 128; t++) {
        if (is_col) {
            const float xpre = pr[c];
            // ---- full-column matvec: z = x + sum_k h[k]*U[k][j] ----
            float a0 = 0.f, a1 = 0.f, a2 = 0.f, a3 = 0.f;
#pragma unroll
            for (int q = 0; q < 16; q++) {
                uint4 hv = h4[q];                       // broadcast b128: h[8q..8q+7]
                unsigned int u0 = ucol[(4 * q + 0) << 7];
                unsigned int u1 = ucol[(4 * q + 1) << 7];
                unsigned int u2 = ucol[(4 * q + 2) << 7];
                unsigned int u3 = ucol[(4 * q + 3) << 7];
                a0 = dot2f(u0, hv.x, a0);
                a1 = dot2f(u1, hv.y, a1);
                a2 = dot2f(u2, hv.z, a2);
                a3 = dot2f(u3, hv.w, a3);
            }
            float z = (a0 + a1) + (a2 + a3) + xpre;
            float g = (m == 2) ? tanhf(z) : hsig_f(z);
            gate_buf[c] = g;
        } else {
            // ---- fre gate: 32 threads per col, 4 k's each (h_buf = old h) ----
            const float xfre = pr[512 + fcol];
            float4 hv = *(const float4*)(&h_buf[kg * 4]);
            float4 uv = *(const float4*)(&ufre_t[fcol * 132 + kg * 4]);
            float p = fmaf(hv.x, uv.x, fmaf(hv.y, uv.y, fmaf(hv.z, uv.z, hv.w * uv.w)));
#pragma unroll
            for (int off = 1; off <= 16; off <<= 1) p += __shfl_xor(p, off, 64);
            if (kg == 0) fre_buf[fcol] = hsig_f(p + xfre);
        }
        __syncthreads();  // B_gates: gates + fre visible

        // ---- state update: thread owns (hh, freqs fsel & fsel+8) ----
        {
            float iv = gate_buf[hh];
            float sv = gate_buf[128 + hh];
            float tc = gate_buf[256 + hh];
            float ov = gate_buf[384 + hh];
            float cg = iv * tc;

            idx0 = (idx0 + fsel) & 15;
            idx1 = (idx1 + fsel + 8) & 15;

            float f0v = sv * fre_buf[fsel];
            float f1v = sv * fre_buf[fsel + 8];
            Sre0 = fmaf(f0v, Sre0, cg * costab[idx0]);
            Sim0 = fmaf(f0v, Sim0, cg * sintab[idx0]);
            Sre1 = fmaf(f1v, Sre1, cg * costab[idx1]);
            Sim1 = fmaf(f1v, Sim1, cg * sintab[idx1]);

            float aacc = fmaf(Sre0, Sre0, Sim0 * Sim0) * ua0;
            aacc = fmaf(fmaf(Sre1, Sre1, Sim1 * Sim1), ua1, aacc);
            aacc += __shfl_xor(aacc, 1, 64);
            aacc += __shfl_xor(aacc, 2, 64);
            aacc += __shfl_xor(aacc, 4, 64);
            if (fsel == 0) {
                float a  = tanhf(aacc + ba);
                float hv = ov * a;
                h_buf[hh] = hv;
                h16[hh]   = __float2half(hv);
            }
        }
        __syncthreads();  // B_h: h ready
        pr += 528;
    }

    // ---- output: out[b] = h @ W_sym + b_sym ----
    if (tid < 64) {
        float v = fmaf(h_buf[tid], Wsym[tid], h_buf[64 + tid] * Wsym[64 + tid]);
#pragma unroll
        for (int off = 1; off <= 32; off <<= 1) v += __shfl_xor(v, off, 64);
        if (tid == 0) out[b] = v + bsym[0];
    }
}

extern "C" void kernel_launch(void* const* d_in, const int* in_sizes, int n_in,
                              void* d_out, int out_size, void* d_ws, size_t ws_size,
                              hipStream_t stream) {
    const float* input = (const float*)d_in[0];
    const float* W_i   = (const float*)d_in[1];
    const float* U_i   = (const float*)d_in[2];
    const float* b_i   = (const float*)d_in[3];
    const float* W_ste = (const float*)d_in[4];
    const float* U_ste = (const float*)d_in[5];
    const float* b_ste = (const float*)d_in[6];
    const float* W_fre = (const float*)d_in[7];
    const float* U_fre = (const float*)d_in[8];
    const float* b_fre = (const float*)d_in[9];
    const float* W_c   = (const float*)d_in[10];
    const float* U_c   = (const float*)d_in[11];
    const float* b_c   = (const float*)d_in[12];
    const float* W_o   = (const float*)d_in[13];
    const float* U_o   = (const float*)d_in[14];
    const float* b_o   = (const float*)d_in[15];
    const float* U_a   = (const float*)d_in[16];
    const float* b_a   = (const float*)d_in[17];
    const float* W_sym = (const float*)d_in[18];
    const float* b_sym = (const float*)d_in[19];

    float* P = (float*)d_ws;  // 32768 x 528 fp32 = 69.2 MB

    proj_gemm<<<512, 256, 0, stream>>>(
        input, W_i, W_ste, W_c, W_o, W_fre,
        b_i, b_ste, b_c, b_o, b_fre, P);

    recur_kernel<<<256, 1024, 0, stream>>>(
        P, U_i, U_ste, U_c, U_o, U_fre,
        U_a, b_a, W_sym, b_sym, (float*)d_out);
}

// Round 14
// 349.630 us; speedup vs baseline: 1.2284x; 1.0407x over previous
//
#include <hip/hip_runtime.h>
#include <hip/hip_bf16.h>
#include <hip/hip_fp16.h>

// SFM model: B=256, T=128, D=128, FREQ=16, HID=128
// Phase 1: P[(b*128+t)*528 + c] = x(b,t,:) @ [W_i|W_ste|W_c|W_o|W_fre] + bias
// Phase 2: sequential scan, 1024 thr/block, 1 batch/block, 2 barriers/step.
//   U in LDS as packed fp16, COLUMN-CONTIGUOUS with XOR swizzle:
//   u_lds[(m*128+j)*64 + (kk ^ ((j&15)<<2))] = {U[2kk][j],U[2kk+1][j]}.
//   Matvec = 16 ds_read_b128 (conflict-free via swizzle) + 64 dot2 per column.
//   Round-13 post-mortem: 512 strided ds_read_b32/step saturated the LDS pipe
//   (~2970 cyc/step, VALUBusy 37%); b128 layout cuts LDS-pipe time ~2x.

typedef _Float16 h2t __attribute__((ext_vector_type(2)));

__device__ __forceinline__ h2t bch(unsigned int v) {
    union { unsigned int u; h2t h; } c; c.u = v; return c.h;
}
__device__ __forceinline__ float dot2f(unsigned int u, unsigned int h, float acc) {
#if __has_builtin(__builtin_amdgcn_fdot2)
    return __builtin_amdgcn_fdot2(bch(u), bch(h), acc, false);
#else
    h2t a = bch(u), b = bch(h);
    acc = fmaf((float)a[0], (float)b[0], acc);
    return fmaf((float)a[1], (float)b[1], acc);
#endif
}

__device__ __forceinline__ float hsig_f(float z) {
    return fminf(fmaxf(z * (1.0f / 6.0f) + 0.5f, 0.0f), 1.0f);
}

// ---------------- Phase 1: projection GEMM ----------------
__global__ __launch_bounds__(256) void proj_gemm(
    const float* __restrict__ input,
    const float* __restrict__ Wi, const float* __restrict__ Wste,
    const float* __restrict__ Wc, const float* __restrict__ Wo,
    const float* __restrict__ Wfre,
    const float* __restrict__ bi, const float* __restrict__ bste,
    const float* __restrict__ bc, const float* __restrict__ bo,
    const float* __restrict__ bfre,
    float* __restrict__ P)
{
    __shared__ __align__(16) float XT[128 * 64];  // [k][t]  32 KB
    __shared__ __align__(16) float WT[128 * 66];  // [k][c]

    const int br  = blockIdx.x;          // 512 blocks: 64 rows each
    const int b   = br >> 1;
    const int t0g = (br & 1) * 64;
    const int tid = threadIdx.x;

    const float* xb = input + (size_t)b * 16384 + t0g;
#pragma unroll
    for (int i = 0; i < 8; i++) {
        int f = (i * 256 + tid) * 4;
        int k = f >> 6, t = f & 63;
        *(float4*)(&XT[k * 64 + t]) = *(const float4*)(xb + k * 128 + t);
    }

    const int tx = tid & 31;   // col pair
    const int ty = tid >> 5;   // rows ty*8 .. ty*8+7

    const float* Ws[5]     = {Wi, Wste, Wc, Wo, Wfre};
    const float* biases[5] = {bi, bste, bc, bo, bfre};

    for (int ct = 0; ct < 5; ct++) {
        const float* W     = Ws[ct];
        const float* bias  = biases[ct];
        const int    ncols = (ct < 4) ? 128 : 16;
        const int    npass = (ct < 4) ? 2 : 1;
        const int    cbase = (ct < 4) ? ct * 128 : 512;

        for (int ch = 0; ch < npass; ch++) {
            __syncthreads();
#pragma unroll
            for (int i = 0; i < 8; i++) {
                int f = (i * 256 + tid) * 4;
                int k = f >> 6, c = f & 63;
                int gc = ch * 64 + c;
                if (gc < ncols)
                    *(float4*)(&WT[k * 66 + c]) = *(const float4*)(W + k * ncols + gc);
            }
            __syncthreads();

            float acc[8][2] = {};
#pragma unroll 4
            for (int k = 0; k < 128; k++) {
                float2 w  = *(const float2*)(&WT[k * 66 + tx * 2]);
                float4 x0 = *(const float4*)(&XT[k * 64 + ty * 8]);
                float4 x1 = *(const float4*)(&XT[k * 64 + ty * 8 + 4]);
                const float xr[8] = {x0.x, x0.y, x0.z, x0.w, x1.x, x1.y, x1.z, x1.w};
#pragma unroll
                for (int r = 0; r < 8; r++) {
                    acc[r][0] = fmaf(xr[r], w.x, acc[r][0]);
                    acc[r][1] = fmaf(xr[r], w.y, acc[r][1]);
                }
            }

            const int colg = ch * 64 + tx * 2;
            if (colg < ncols) {
                float b0 = bias[colg], b1 = bias[colg + 1];
#pragma unroll
                for (int r = 0; r < 8; r++) {
                    int row = br * 64 + ty * 8 + r;
                    float2 o = make_float2(acc[r][0] + b0, acc[r][1] + b1);
                    *(float2*)(&P[(size_t)row * 528 + cbase + colg]) = o;
                }
            }
        }
    }
}

// ---------------- Phase 2: sequential recurrence ----------------
// 1024 threads. tid<512: full-column matvec+gate (c=tid, m=c>>7, j=c&127).
// tid>=512: fre gate (fcol=(tid-512)>>5, kg=(tid-512)&31).
// State: hh = tid>>3 (0..127), fsel = tid&7 -> freqs {fsel, fsel+8}.
// U LDS: column-contiguous + XOR swizzle (see header comment).
__global__ __launch_bounds__(1024) void recur_kernel(
    const float* __restrict__ P,
    const float* __restrict__ Ui, const float* __restrict__ Uste,
    const float* __restrict__ Uc, const float* __restrict__ Uo,
    const float* __restrict__ Ufre,
    const float* __restrict__ Ua, const float* __restrict__ ba_g,
    const float* __restrict__ Wsym, const float* __restrict__ bsym,
    float* __restrict__ out)
{
    __shared__ __align__(16) unsigned int u_lds[4 * 128 * 64];  // 128 KB [col][p]
    __shared__ __align__(16) float ufre_t[16 * 132];            // [col][k]
    __shared__ __align__(16) __half h16[128];                   // h as fp16
    __shared__ float costab[16], sintab[16];
    __shared__ float gate_buf[512];                             // [i|ste|c|o] x 128
    __shared__ float fre_buf[16];
    __shared__ float h_buf[128];

    const int tid  = threadIdx.x;
    const int b    = blockIdx.x;
    const int hh   = tid >> 3;     // 0..127
    const int fsel = tid & 7;      // freqs fsel, fsel+8

    const bool is_col = (tid < 512);
    const int  c    = tid & 511;   // col id (col threads)
    const int  m    = c >> 7;
    const int  j    = c & 127;
    const int  fcol = c >> 5;      // fre col (fre threads): 0..15
    const int  kg   = c & 31;      // fre k-group

    // ---- one-time LDS init ----
    // u_lds[col*64 + p] with p = kk ^ ((j&15)<<2): physical slot p holds kpair kk.
    for (int e = tid; e < 4 * 128 * 64; e += 1024) {
        int col = e >> 6, p = e & 63;
        int jj = col & 127, m_ = col >> 7;
        int kk = p ^ ((jj & 15) << 2);
        const float* Um = (m_ == 0) ? Ui : (m_ == 1) ? Uste : (m_ == 2) ? Uc : Uo;
        union { h2t h; unsigned int u; } pk;
        pk.h[0] = (_Float16)Um[(2 * kk) * 128 + jj];
        pk.h[1] = (_Float16)Um[(2 * kk + 1) * 128 + jj];
        u_lds[e] = pk.u;
    }
    for (int e = tid; e < 2048; e += 1024) {
        int k = e >> 4, col = e & 15;
        ufre_t[col * 132 + k] = Ufre[e];
    }
    if (tid < 16) {
        float ang = 6.283185307179586f * (float)tid * (1.0f / 16.0f);
        costab[tid] = cosf(ang);
        sintab[tid] = sinf(ang);
    }
    if (tid < 128) { h_buf[tid] = 0.0f; h16[tid] = __float2half(0.0f); }

    const float ua0 = Ua[fsel];
    const float ua1 = Ua[fsel + 8];
    const float ba  = ba_g[hh];

    float Sre0 = 0.f, Sim0 = 0.f, Sre1 = 0.f, Sim1 = 0.f;
    int idx0 = 0, idx1 = 0;

    __syncthreads();

    const unsigned int* ucol = u_lds + ((m << 7) + j) * 64;  // this thread's column
    const int swz = (j & 15) << 2;
    const uint4* h4 = (const uint4*)h16;                     // 16 x (8 halves), uniform

    const float* pr = P + (size_t)b * 128 * 528;
    for (int t = 0; t < 128; t++) {
        if (is_col) {
            const float xpre = pr[c];
            // ---- full-column matvec: z = x + sum_k h[k]*U[k][j] ----
            // 16 x ds_read_b128 (swizzled, conflict-free) + 64 dot2
            float a0 = 0.f, a1 = 0.f, a2 = 0.f, a3 = 0.f;
#pragma unroll
            for (int q = 0; q < 16; q++) {
                uint4 uu = *(const uint4*)(ucol + ((4 * q) ^ swz));  // kpairs 4q..4q+3
                uint4 hv = h4[q];                                    // h[8q..8q+7]
                a0 = dot2f(uu.x, hv.x, a0);
                a1 = dot2f(uu.y, hv.y, a1);
                a2 = dot2f(uu.z, hv.z, a2);
                a3 = dot2f(uu.w, hv.w, a3);
            }
            float z = (a0 + a1) + (a2 + a3) + xpre;
            float g = (m == 2) ? tanhf(z) : hsig_f(z);
            gate_buf[c] = g;
        } else {
            // ---- fre gate: 32 threads per col, 4 k's each (h_buf = old h) ----
            const float xfre = pr[512 + fcol];
            float4 hv = *(const float4*)(&h_buf[kg * 4]);
            float4 uv = *(const float4*)(&ufre_t[fcol * 132 + kg * 4]);
            float p = fmaf(hv.x, uv.x, fmaf(hv.y, uv.y, fmaf(hv.z, uv.z, hv.w * uv.w)));
#pragma unroll
            for (int off = 1; off <= 16; off <<= 1) p += __shfl_xor(p, off, 64);
            if (kg == 0) fre_buf[fcol] = hsig_f(p + xfre);
        }
        __syncthreads();  // B_gates: gates + fre visible

        // ---- state update: thread owns (hh, freqs fsel & fsel+8) ----
        {
            float iv = gate_buf[hh];
            float sv = gate_buf[128 + hh];
            float tc = gate_buf[256 + hh];
            float ov = gate_buf[384 + hh];
            float cg = iv * tc;

            idx0 = (idx0 + fsel) & 15;
            idx1 = (idx1 + fsel + 8) & 15;

            float f0v = sv * fre_buf[fsel];
            float f1v = sv * fre_buf[fsel + 8];
            Sre0 = fmaf(f0v, Sre0, cg * costab[idx0]);
            Sim0 = fmaf(f0v, Sim0, cg * sintab[idx0]);
            Sre1 = fmaf(f1v, Sre1, cg * costab[idx1]);
            Sim1 = fmaf(f1v, Sim1, cg * sintab[idx1]);

            float aacc = fmaf(Sre0, Sre0, Sim0 * Sim0) * ua0;
            aacc = fmaf(fmaf(Sre1, Sre1, Sim1 * Sim1), ua1, aacc);
            aacc += __shfl_xor(aacc, 1, 64);
            aacc += __shfl_xor(aacc, 2, 64);
            aacc += __shfl_xor(aacc, 4, 64);
            if (fsel == 0) {
                float a  = tanhf(aacc + ba);
                float hv = ov * a;
                h_buf[hh] = hv;
                h16[hh]   = __float2half(hv);
            }
        }
        __syncthreads();  // B_h: h ready
        pr += 528;
    }

    // ---- output: out[b] = h @ W_sym + b_sym ----
    if (tid < 64) {
        float v = fmaf(h_buf[tid], Wsym[tid], h_buf[64 + tid] * Wsym[64 + tid]);
#pragma unroll
        for (int off = 1; off <= 32; off <<= 1) v += __shfl_xor(v, off, 64);
        if (tid == 0) out[b] = v + bsym[0];
    }
}

extern "C" void kernel_launch(void* const* d_in, const int* in_sizes, int n_in,
                              void* d_out, int out_size, void* d_ws, size_t ws_size,
                              hipStream_t stream) {
    const float* input = (const float*)d_in[0];
    const float* W_i   = (const float*)d_in[1];
    const float* U_i   = (const float*)d_in[2];
    const float* b_i   = (const float*)d_in[3];
    const float* W_ste = (const float*)d_in[4];
    const float* U_ste = (const float*)d_in[5];
    const float* b_ste = (const float*)d_in[6];
    const float* W_fre = (const float*)d_in[7];
    const float* U_fre = (const float*)d_in[8];
    const float* b_fre = (const float*)d_in[9];
    const float* W_c   = (const float*)d_in[10];
    const float* U_c   = (const float*)d_in[11];
    const float* b_c   = (const float*)d_in[12];
    const float* W_o   = (const float*)d_in[13];
    const float* U_o   = (const float*)d_in[14];
    const float* b_o   = (const float*)d_in[15];
    const float* U_a   = (const float*)d_in[16];
    const float* b_a   = (const float*)d_in[17];
    const float* W_sym = (const float*)d_in[18];
    const float* b_sym = (const float*)d_in[19];

    float* P = (float*)d_ws;  // 32768 x 528 fp32 = 69.2 MB

    proj_gemm<<<512, 256, 0, stream>>>(
        input, W_i, W_ste, W_c, W_o, W_fre,
        b_i, b_ste, b_c, b_o, b_fre, P);

    recur_kernel<<<256, 1024, 0, stream>>>(
        P, U_i, U_ste, U_c, U_o, U_fre,
        U_a, b_a, W_sym, b_sym, (float*)d_out);
}